// Round 4
// baseline (589.338 us; speedup 1.0000x reference)
//
#include <hip/hip_runtime.h>
#include <hip/hip_bf16.h>

#define H 1024
#define B 32
#define S 2048

typedef __attribute__((ext_vector_type(8))) short bf16x8;
typedef __attribute__((ext_vector_type(4))) float f32x4;

union U4 { uint4 u; bf16x8 b; };

__device__ __forceinline__ unsigned short f2bf(float f) {
    unsigned u = __float_as_uint(f);
    unsigned r = (u + 0x7fffu + ((u >> 16) & 1u)) >> 16;
    return (unsigned short)r;
}

__device__ __forceinline__ uint4 pack8(float4 x, float4 y) {
    uint4 p;
    p.x = (unsigned)f2bf(x.x) | ((unsigned)f2bf(x.y) << 16);
    p.y = (unsigned)f2bf(x.z) | ((unsigned)f2bf(x.w) << 16);
    p.z = (unsigned)f2bf(y.x) | ((unsigned)f2bf(y.y) << 16);
    p.w = (unsigned)f2bf(y.z) | ((unsigned)f2bf(y.w) << 16);
    return p;
}

__device__ __forceinline__ float ftanh(float x) {
    float x2 = __builtin_amdgcn_fmed3f(x + x, -30.f, 30.f);
    float e = __expf(x2);
    return 1.f - 2.f * __builtin_amdgcn_rcpf(e + 1.f);
}

__device__ __forceinline__ void async_copy16(const void* g, void* l) {
    __builtin_amdgcn_global_load_lds(
        (const __attribute__((address_space(1))) unsigned int*)g,
        (__attribute__((address_space(3))) unsigned int*)l, 16, 0, 0);
}

// ---------------------------------------------------------------------------
// K0: Ua_w fp32 [n][k] -> bf16 MFMA-B-frag order: UaSw[nb(8)][kc(32)][nt(8)*64+lane]
__global__ void k0_swizzle(const float* __restrict__ Ua, uint4* __restrict__ UaSw) {
    int t = blockIdx.x * 256 + threadIdx.x;   // 0..131071
    int lane = t & 63;
    int nt = (t >> 6) & 7;
    int kc = (t >> 9) & 31;
    int nb = t >> 14;
    int n = nb * 128 + nt * 16 + (lane & 15);
    int k = kc * 32 + ((lane >> 4) & 3) * 8;
    const float4* src = (const float4*)(Ua + (size_t)n * H + k);
    UaSw[t] = pack8(src[0], src[1]);
}

// ---------------------------------------------------------------------------
// KA: keys fp32 [b*S+s][h] -> bf16 MFMA A-frag order:
// Abf[g], g = (stile*32 + kc)*64 + lane; stile = (b*S+s)/16
// row = stile*16 + (lane&15); col = kc*32 + ((lane>>4)&3)*8 + j
__global__ __launch_bounds__(256) void ka_swz(const float* __restrict__ keys,
                                              uint4* __restrict__ Abf) {
    size_t g = (size_t)blockIdx.x * 256 + threadIdx.x;   // 0..8388607
    int lane = (int)(g & 63);
    size_t u = g >> 6;
    int kc = (int)(u & 31);
    size_t stile = u >> 5;                                // 0..4095
    size_t row = stile * 16 + (lane & 15);
    int col = kc * 32 + ((lane >> 4) & 3) * 8;
    const float4* src = (const float4*)(keys + row * H + col);
    Abf[g] = pack8(src[0], src[1]);
}

// ---------------------------------------------------------------------------
// K1: qp[b][n] = sum_h query[b][h]*Wa_w[n][h] + Wa_b[n] + Ua_b[n]
__global__ __launch_bounds__(256) void k1_qproj(
    const float* __restrict__ q, const float* __restrict__ Wa,
    const float* __restrict__ Wab, const float* __restrict__ Uab,
    float* __restrict__ qp) {
    int b = blockIdx.y;
    int t = threadIdx.x;
    int n = blockIdx.x * 64 + (t >> 2);
    int quarter = t & 3;
    __shared__ float qs[H];
    for (int i = t; i < H; i += 256) qs[i] = q[b * H + i];
    __syncthreads();
    const float4* wr = (const float4*)(Wa + (size_t)n * H + quarter * 256);
    const float* qq = qs + quarter * 256;
    float acc = 0.f;
#pragma unroll 4
    for (int i = 0; i < 64; i++) {
        float4 w = wr[i];
        acc += qq[i * 4 + 0] * w.x + qq[i * 4 + 1] * w.y +
               qq[i * 4 + 2] * w.z + qq[i * 4 + 3] * w.w;
    }
    acc += __shfl_xor(acc, 1, 64);
    acc += __shfl_xor(acc, 2, 64);
    if (quarter == 0) qp[b * H + n] = acc + Wab[n] + Uab[n];
}

// ---------------------------------------------------------------------------
// K2v6: fully LDS-staged streaming GEMM, counted-vmcnt pipeline (T3+T4+T5).
// Block = 128 rows x 128 n (one nb), 4 waves, wave w owns 2 m-tiles x 8 n-tiles
// (acc 2x8 f32x4 = 64 AGPR; proven footprint). BOTH A and B staged via
// global_load_lds: per kc-tile A=8KB + B=8KB; 3 buffers (48 KB LDS, 3 blk/CU),
// prefetch distance 2. Per step each thread issues exactly 4 async copies
// (2 A + 2 B); the ONLY vmem wait in the loop is the boundary
// s_waitcnt vmcnt(4) (tile t+1 landed, t+2's 4 ops stay in flight) -- the
// round-3 A register stream is gone, so the compiler has no dependent-use
// wait to insert that would drain the queue. Frag reads = 10 ds_read_b128 at
// lane*16B (conflict-free, m97 pattern), lgkm-covered by MFMA deps.
// Hazard: stage(t+2) targets buf (t+2)%3 == buf of tile t-1, whose ds_reads
// all completed before the end-of-step-(t-1) barrier (MFMAs consumed them,
// pinned before the boundary by sched_barrier(0)); stage is issued after it.
__global__ __launch_bounds__(256, 3) void k2_scores6(
    const uint4* __restrict__ Abf, const uint4* __restrict__ UaSw,
    const float* __restrict__ qp, const float* __restrict__ Vaw,
    float* __restrict__ sp) {
    __shared__ uint4 abuf[3][512];   // 24 KB
    __shared__ uint4 bbuf[3][512];   // 24 KB
    const int tid = threadIdx.x;
    const int lane = tid & 63;
    const int w = tid >> 6;          // wave id == m-tile-pair owner
    const int lid = blockIdx.x;      // 0..4095
    const int c = lid & 7;           // XCD slot (round-robin by linear id)
    const int qq = lid >> 3;
    const int nb = qq & 7;           // nb cycles fastest within an XCD
    const int mb = (qq >> 3) * 8 + c;
    const int b = mb >> 4;
    const int s0 = (mb & 15) << 7;

    // A panel for this block: stiles mb*8 .. mb*8+7; chunk (st,kc) at
    // pag[(st*32+kc)*64 + lane]. B panel: pbg[kc*512 + nt*64 + lane].
    const uint4* pag = Abf + (size_t)(mb * 8) * 2048;
    const uint4* pbg = UaSw + (size_t)nb * 16384;

    f32x4 acc[2][8];
#pragma unroll
    for (int mt = 0; mt < 2; mt++)
#pragma unroll
        for (int nt = 0; nt < 8; nt++) acc[mt][nt] = (f32x4){0.f, 0.f, 0.f, 0.f};

    // stage tile kt into buffer bs: 4 async copies per thread
    auto STAGE = [&](int kt, int bs) {
        async_copy16(pag + ((size_t)(w * 32) + kt) * 64 + lane,
                     &abuf[bs][w * 64 + lane]);
        async_copy16(pag + ((size_t)((w + 4) * 32) + kt) * 64 + lane,
                     &abuf[bs][(w + 4) * 64 + lane]);
        async_copy16(pbg + (size_t)kt * 512 + tid, &bbuf[bs][tid]);
        async_copy16(pbg + (size_t)kt * 512 + 256 + tid, &bbuf[bs][tid + 256]);
    };

    // prologue: tiles 0,1 in flight (8 ops); vmcnt(4) -> tile 0 landed
    STAGE(0, 0);
    __builtin_amdgcn_sched_barrier(0);
    STAGE(1, 1);
    __builtin_amdgcn_sched_barrier(0);
    asm volatile("s_waitcnt vmcnt(4)" ::: "memory");
    __builtin_amdgcn_s_barrier();
    __builtin_amdgcn_sched_barrier(0);

    int bi = 0, bs = 2;
    for (int t = 0; t < 32; ++t) {
        // issue prefetch for tile t+2 (tail wraps: redundant re-stage of 0,1)
        STAGE((t + 2) & 31, bs);

        // frags for tile t from LDS (landed: guaranteed by previous boundary)
        U4 a0, a1, bb[8];
        a0.u = abuf[bi][(w * 2 + 0) * 64 + lane];
        a1.u = abuf[bi][(w * 2 + 1) * 64 + lane];
#pragma unroll
        for (int nt = 0; nt < 8; nt++) bb[nt].u = bbuf[bi][nt * 64 + lane];

        __builtin_amdgcn_s_setprio(1);
#pragma unroll
        for (int nt = 0; nt < 8; nt++) {
            acc[0][nt] = __builtin_amdgcn_mfma_f32_16x16x32_bf16(
                a0.b, bb[nt].b, acc[0][nt], 0, 0, 0);
            acc[1][nt] = __builtin_amdgcn_mfma_f32_16x16x32_bf16(
                a1.b, bb[nt].b, acc[1][nt], 0, 0, 0);
        }
        __builtin_amdgcn_s_setprio(0);

        // boundary: tile t+1 (issued 1 step ago) guaranteed landed; tile t+2's
        // 4 ops stay in flight across the barrier. Never vmcnt(0) in-loop.
        __builtin_amdgcn_sched_barrier(0);
        asm volatile("s_waitcnt vmcnt(4)" ::: "memory");
        __builtin_amdgcn_s_barrier();
        __builtin_amdgcn_sched_barrier(0);

        bi = (bi == 2) ? 0 : bi + 1;
        bs = (bs == 2) ? 0 : bs + 1;
    }
    asm volatile("s_waitcnt vmcnt(0)" ::: "memory");   // drain tail stages

    // epilogue: tanh, dot Va, shfl-reduce over col(16), direct store (disjoint rows)
    const int col = lane & 15, qd = lane >> 4;
    float qv[8], vv[8];
#pragma unroll
    for (int nt = 0; nt < 8; nt++) {
        int n = nb * 128 + nt * 16 + col;
        qv[nt] = qp[b * H + n];
        vv[nt] = Vaw[n];
    }
#pragma unroll
    for (int mt = 0; mt < 2; mt++) {
        float rs[4] = {0.f, 0.f, 0.f, 0.f};
#pragma unroll
        for (int nt = 0; nt < 8; nt++)
#pragma unroll
            for (int r = 0; r < 4; r++)
                rs[r] += ftanh(acc[mt][nt][r] + qv[nt]) * vv[nt];
#pragma unroll
        for (int r = 0; r < 4; r++) {
            float v = rs[r];
            v += __shfl_xor(v, 1, 64);
            v += __shfl_xor(v, 2, 64);
            v += __shfl_xor(v, 4, 64);
            v += __shfl_xor(v, 8, 64);
            if (col == 0)
                sp[(size_t)nb * B * S + b * S + s0 + w * 32 + mt * 16 + qd * 4 + r] = v;
        }
    }
}

// ---------------------------------------------------------------------------
// K4v2: fused partial-sum + softmax + weights-write + context from bf16 keys.
// grid (8,32): block (kcg,b); wave wv handles kc=kcg*4+wv. Each (b,kc,q,j)
// owns unique context cols -> plain stores, no pre-zero needed.
__global__ __launch_bounds__(256) void k4_ctx2(const uint4* __restrict__ Abf,
                                               const float* __restrict__ sp,
                                               float* __restrict__ out) {
    int kcg = blockIdx.x, b = blockIdx.y;
    int t = threadIdx.x;
    __shared__ float red[256];
    __shared__ float wl[S];   // 8 KB

    float v[8];
#pragma unroll
    for (int i = 0; i < 8; i++) {
        int s = i * 256 + t;
        float sum = 0.f;
#pragma unroll
        for (int nb = 0; nb < 8; nb++) sum += sp[(size_t)nb * B * S + b * S + s];
        v[i] = sum;
    }
    float lm = -1e30f;
#pragma unroll
    for (int i = 0; i < 8; i++) lm = fmaxf(lm, v[i]);
    red[t] = lm;
    __syncthreads();
    for (int s = 128; s > 0; s >>= 1) {
        if (t < s) red[t] = fmaxf(red[t], red[t + s]);
        __syncthreads();
    }
    float m = red[0];
    __syncthreads();
    float ls = 0.f;
#pragma unroll
    for (int i = 0; i < 8; i++) ls += __expf(v[i] - m);
    red[t] = ls;
    __syncthreads();
    for (int s = 128; s > 0; s >>= 1) {
        if (t < s) red[t] += red[t + s];
        __syncthreads();
    }
    float inv = 1.f / red[0];
#pragma unroll
    for (int i = 0; i < 8; i++) {
        int s = i * 256 + t;
        float w = __expf(v[i] - m) * inv;
        wl[s] = w;
        if (kcg == 0) out[B * H + b * S + s] = w;
    }
    __syncthreads();

    const int wv = t >> 6, lane = t & 63, qd = lane >> 4, colr = lane & 15;
    const int kc = kcg * 4 + wv;
    float a8[8] = {0.f, 0.f, 0.f, 0.f, 0.f, 0.f, 0.f, 0.f};
    const uint4* base = Abf + ((size_t)(b * 128) * 32 + kc) * 64 + lane;
#pragma unroll 4
    for (int st = 0; st < 128; st++) {
        uint4 f = base[(size_t)st * 2048];
        float w = wl[st * 16 + colr];
        a8[0] += w * __uint_as_float(f.x << 16);
        a8[1] += w * __uint_as_float(f.x & 0xffff0000u);
        a8[2] += w * __uint_as_float(f.y << 16);
        a8[3] += w * __uint_as_float(f.y & 0xffff0000u);
        a8[4] += w * __uint_as_float(f.z << 16);
        a8[5] += w * __uint_as_float(f.z & 0xffff0000u);
        a8[6] += w * __uint_as_float(f.w << 16);
        a8[7] += w * __uint_as_float(f.w & 0xffff0000u);
    }
#pragma unroll
    for (int j = 0; j < 8; j++) {
        float vj = a8[j];
        vj += __shfl_xor(vj, 1, 64);
        vj += __shfl_xor(vj, 2, 64);
        vj += __shfl_xor(vj, 4, 64);
        vj += __shfl_xor(vj, 8, 64);
        a8[j] = vj;
    }
    if (colr == 0) {
        int colbase = kc * 32 + qd * 8;
#pragma unroll
        for (int j = 0; j < 8; j++) out[b * H + colbase + j] = a8[j];
    }
}

// ===========================================================================
// Fallback path (ws too small): round-4 kernels
// ===========================================================================
__global__ __launch_bounds__(256, 3) void k2_scores_fb(
    const float* __restrict__ keys, const uint4* __restrict__ UaSw,
    const float* __restrict__ qp, const float* __restrict__ Vaw,
    float* __restrict__ sp) {
    __shared__ uint4 As[2][512];
    __shared__ uint4 Bs[2][512];
    __shared__ float part[2][128];
    const int tid = threadIdx.x;
    const int lane = tid & 63;
    const int wave = tid >> 6;
    const int wm = wave >> 1, wn = wave & 1;
    const int lid = blockIdx.x;
    const int c = lid & 7;
    const int qq = lid >> 3;
    const int nb = qq & 7;
    const int mb = (qq >> 3) * 8 + c;
    const int b = mb >> 4;
    const int s0 = (mb & 15) << 7;
    const int el = tid & 63;
    const int srow0 = s0 + (tid >> 6) * 16 + (el & 15);
    const int srow1 = srow0 + 64;
    const int kofs = ((el >> 4) & 3) * 8;
    const float4* ka0 = (const float4*)(keys + ((size_t)b * S + srow0) * H + kofs);
    const float4* ka1 = (const float4*)(keys + ((size_t)b * S + srow1) * H + kofs);
    const uint4* srcB = UaSw + (size_t)nb * 32 * 512;
    f32x4 acc[4][4];
#pragma unroll
    for (int mt = 0; mt < 4; mt++)
#pragma unroll
        for (int nt = 0; nt < 4; nt++) acc[mt][nt] = (f32x4){0.f, 0.f, 0.f, 0.f};
    float4 x0 = ka0[0], y0 = ka0[1], x1 = ka1[0], y1 = ka1[1];
    async_copy16(srcB + tid,       &Bs[0][tid]);
    async_copy16(srcB + tid + 256, &Bs[0][tid + 256]);
    As[0][tid]       = pack8(x0, y0);
    As[0][tid + 256] = pack8(x1, y1);
    x0 = ka0[8]; y0 = ka0[9]; x1 = ka1[8]; y1 = ka1[9];
    __syncthreads();
    for (int kc = 0; kc < 32; kc++) {
        const int cur = kc & 1, nxt = cur ^ 1;
        if (kc < 31) {
            async_copy16(srcB + (size_t)(kc + 1) * 512 + tid,       &Bs[nxt][tid]);
            async_copy16(srcB + (size_t)(kc + 1) * 512 + tid + 256, &Bs[nxt][tid + 256]);
            As[nxt][tid]       = pack8(x0, y0);
            As[nxt][tid + 256] = pack8(x1, y1);
            if (kc < 30) {
                x0 = ka0[(kc + 2) * 8]; y0 = ka0[(kc + 2) * 8 + 1];
                x1 = ka1[(kc + 2) * 8]; y1 = ka1[(kc + 2) * 8 + 1];
            }
        }
        U4 af[4], bf[4];
#pragma unroll
        for (int mt = 0; mt < 4; mt++) af[mt].u = As[cur][(wm * 4 + mt) * 64 + lane];
#pragma unroll
        for (int nt = 0; nt < 4; nt++) bf[nt].u = Bs[cur][(wn * 4 + nt) * 64 + lane];
#pragma unroll
        for (int mt = 0; mt < 4; mt++)
#pragma unroll
            for (int nt = 0; nt < 4; nt++)
                acc[mt][nt] = __builtin_amdgcn_mfma_f32_16x16x32_bf16(
                    af[mt].b, bf[nt].b, acc[mt][nt], 0, 0, 0);
        __syncthreads();
    }
    const int col = lane & 15, qd = lane >> 4;
    float qv[4], vv[4];
#pragma unroll
    for (int nt = 0; nt < 4; nt++) {
        int n = nb * 128 + (wn * 4 + nt) * 16 + col;
        qv[nt] = qp[b * H + n];
        vv[nt] = Vaw[n];
    }
#pragma unroll
    for (int mt = 0; mt < 4; mt++) {
        float rs[4] = {0.f, 0.f, 0.f, 0.f};
#pragma unroll
        for (int nt = 0; nt < 4; nt++)
#pragma unroll
            for (int r = 0; r < 4; r++)
                rs[r] += ftanh(acc[mt][nt][r] + qv[nt]) * vv[nt];
#pragma unroll
        for (int r = 0; r < 4; r++) {
            float v = rs[r];
            v += __shfl_xor(v, 1, 64);
            v += __shfl_xor(v, 2, 64);
            v += __shfl_xor(v, 4, 64);
            v += __shfl_xor(v, 8, 64);
            if (col == 0) part[wn][wm * 64 + mt * 16 + qd * 4 + r] = v;
        }
    }
    __syncthreads();
    if (tid < 128)
        sp[(size_t)nb * B * S + b * S + s0 + tid] = part[0][tid] + part[1][tid];
}

__global__ __launch_bounds__(256) void k4_ctx_fb(const float* __restrict__ keys,
                                                 const float* __restrict__ sp,
                                                 float* __restrict__ out) {
    int sc = blockIdx.x, b = blockIdx.y;
    int t = threadIdx.x;
    __shared__ float red[256];
    __shared__ float wl[64];
    float v[8];
#pragma unroll
    for (int i = 0; i < 8; i++) {
        int s = i * 256 + t;
        float sum = 0.f;
#pragma unroll
        for (int nb = 0; nb < 8; nb++) sum += sp[(size_t)nb * B * S + b * S + s];
        v[i] = sum;
    }
    float lm = -1e30f;
#pragma unroll
    for (int i = 0; i < 8; i++) lm = fmaxf(lm, v[i]);
    red[t] = lm;
    __syncthreads();
    for (int s = 128; s > 0; s >>= 1) {
        if (t < s) red[t] = fmaxf(red[t], red[t + s]);
        __syncthreads();
    }
    float m = red[0];
    __syncthreads();
    float ls = 0.f;
#pragma unroll
    for (int i = 0; i < 8; i++) ls += __expf(v[i] - m);
    red[t] = ls;
    __syncthreads();
    for (int s = 128; s > 0; s >>= 1) {
        if (t < s) red[t] += red[t + s];
        __syncthreads();
    }
    float inv = 1.f / red[0];
    if (t < 64) {
        int s = sc * 64 + t;
        float sum = 0.f;
#pragma unroll
        for (int nb = 0; nb < 8; nb++) sum += sp[(size_t)nb * B * S + b * S + s];
        float w = __expf(sum - m) * inv;
        wl[t] = w;
        out[B * H + b * S + s] = w;
    }
    __syncthreads();
    const float4* kp = (const float4*)(keys + ((size_t)b * S + sc * 64) * H) + t;
    float4 acc = {0.f, 0.f, 0.f, 0.f};
#pragma unroll 8
    for (int s = 0; s < 64; s++) {
        float4 kv = kp[(size_t)s * 256];
        float w = wl[s];
        acc.x += w * kv.x; acc.y += w * kv.y;
        acc.z += w * kv.z; acc.w += w * kv.w;
    }
    float* dst = out + b * H + t * 4;
    atomicAdd(dst + 0, acc.x);
    atomicAdd(dst + 1, acc.y);
    atomicAdd(dst + 2, acc.z);
    atomicAdd(dst + 3, acc.w);
}

// ---------------------------------------------------------------------------
extern "C" void kernel_launch(void* const* d_in, const int* in_sizes, int n_in,
                              void* d_out, int out_size, void* d_ws, size_t ws_size,
                              hipStream_t stream) {
    const float* query = (const float*)d_in[0];
    const float* keys  = (const float*)d_in[1];
    const float* Wa_w  = (const float*)d_in[2];
    const float* Wa_b  = (const float*)d_in[3];
    const float* Ua_w  = (const float*)d_in[4];
    const float* Ua_b  = (const float*)d_in[5];
    const float* Va_w  = (const float*)d_in[6];
    float* out = (float*)d_out;

    // ws: [0,2MB) UaSw; [2MB,+128KB) qp; [2MB+128KB,+2MB) sp; [8MB,+128MB) Abf
    uint4* UaSw = (uint4*)d_ws;
    float* qp = (float*)((char*)d_ws + (2u << 20));
    float* sp = (float*)((char*)d_ws + (2u << 20) + (128u << 10));
    uint4* Abf = (uint4*)((char*)d_ws + (8u << 20));
    const size_t NEED = (size_t)(8u << 20) + ((size_t)128u << 20);

    if (ws_size >= NEED) {
        ka_swz<<<32768, 256, 0, stream>>>(keys, Abf);
        k0_swizzle<<<512, 256, 0, stream>>>(Ua_w, UaSw);
        k1_qproj<<<dim3(16, B), 256, 0, stream>>>(query, Wa_w, Wa_b, Ua_b, qp);
        k2_scores6<<<4096, 256, 0, stream>>>(Abf, UaSw, qp, Va_w, sp);
        k4_ctx2<<<dim3(8, B), 256, 0, stream>>>(Abf, sp, out);
    } else {
        hipMemsetAsync(d_out, 0, B * H * sizeof(float), stream);
        k0_swizzle<<<512, 256, 0, stream>>>(Ua_w, UaSw);
        k1_qproj<<<dim3(16, B), 256, 0, stream>>>(query, Wa_w, Wa_b, Ua_b, qp);
        k2_scores_fb<<<4096, 256, 0, stream>>>(keys, UaSw, qp, Va_w, sp);
        k4_ctx_fb<<<dim3(32, B), 256, 0, stream>>>(keys, sp, out);
    }
}

// Round 5
// 587.088 us; speedup vs baseline: 1.0038x; 1.0038x over previous
//
#include <hip/hip_runtime.h>
#include <hip/hip_bf16.h>

#define H 1024
#define B 32
#define S 2048

typedef __attribute__((ext_vector_type(8))) short bf16x8;
typedef __attribute__((ext_vector_type(4))) float f32x4;

union U4 { uint4 u; bf16x8 b; };

__device__ __forceinline__ unsigned short f2bf(float f) {
    unsigned u = __float_as_uint(f);
    unsigned r = (u + 0x7fffu + ((u >> 16) & 1u)) >> 16;
    return (unsigned short)r;
}

__device__ __forceinline__ uint4 pack8(float4 x, float4 y) {
    uint4 p;
    p.x = (unsigned)f2bf(x.x) | ((unsigned)f2bf(x.y) << 16);
    p.y = (unsigned)f2bf(x.z) | ((unsigned)f2bf(x.w) << 16);
    p.z = (unsigned)f2bf(y.x) | ((unsigned)f2bf(y.y) << 16);
    p.w = (unsigned)f2bf(y.z) | ((unsigned)f2bf(y.w) << 16);
    return p;
}

__device__ __forceinline__ float ftanh(float x) {
    float x2 = __builtin_amdgcn_fmed3f(x + x, -30.f, 30.f);
    float e = __expf(x2);
    return 1.f - 2.f * __builtin_amdgcn_rcpf(e + 1.f);
}

__device__ __forceinline__ void async_copy16(const void* g, void* l) {
    __builtin_amdgcn_global_load_lds(
        (const __attribute__((address_space(1))) unsigned int*)g,
        (__attribute__((address_space(3))) unsigned int*)l, 16, 0, 0);
}

#define BAR() do { __builtin_amdgcn_sched_barrier(0); \
                   __builtin_amdgcn_s_barrier(); \
                   __builtin_amdgcn_sched_barrier(0); } while (0)

// ---------------------------------------------------------------------------
// K0: Ua_w fp32 [n][k] -> bf16 MFMA-B-frag order: UaSw[nb(8)][kc(32)][nt(8)*64+lane]
__global__ void k0_swizzle(const float* __restrict__ Ua, uint4* __restrict__ UaSw) {
    int t = blockIdx.x * 256 + threadIdx.x;   // 0..131071
    int lane = t & 63;
    int nt = (t >> 6) & 7;
    int kc = (t >> 9) & 31;
    int nb = t >> 14;
    int n = nb * 128 + nt * 16 + (lane & 15);
    int k = kc * 32 + ((lane >> 4) & 3) * 8;
    const float4* src = (const float4*)(Ua + (size_t)n * H + k);
    UaSw[t] = pack8(src[0], src[1]);
}

// ---------------------------------------------------------------------------
// KA2: keys fp32 -> bf16 MFMA A-frag order, via LDS transpose (both global
// sides coalesced). Block = 1 stile (16 rows x 1024 cols). Phase 1: 16 f4 per
// thread, contiguous 1KB/wave reads, convert, ds_write_b64 into [16][1032]
// bf16 (row stride 2064 B = 16B-aligned, +4-bank stagger). Phase 2: 8 frag
// chunks per thread read from LDS as uint4, written contiguous (32 KB/block).
__global__ __launch_bounds__(256) void ka_swz2(const float* __restrict__ keys,
                                               uint4* __restrict__ Abf) {
    __shared__ unsigned short lb[16][1032];   // 33 KB
    const int t = threadIdx.x;
    const size_t blk = blockIdx.x;            // 0..4095 (stile)
    const float4* src = (const float4*)keys + blk * 4096;   // 16 rows x 256 f4
#pragma unroll
    for (int i = 0; i < 16; ++i) {
        int f = i * 256 + t;                  // 0..4095
        float4 v = src[f];
        int row = f >> 8;
        int c4 = (f & 255) << 2;
        uint2 pk;
        pk.x = (unsigned)f2bf(v.x) | ((unsigned)f2bf(v.y) << 16);
        pk.y = (unsigned)f2bf(v.z) | ((unsigned)f2bf(v.w) << 16);
        *(uint2*)&lb[row][c4] = pk;
    }
    __syncthreads();
    uint4* dst = Abf + blk * 2048;
#pragma unroll
    for (int i = 0; i < 8; ++i) {
        int cidx = i * 256 + t;               // 0..2047 = kc*64 + lane
        int lane = cidx & 63;
        int kc = cidx >> 6;
        dst[cidx] = *(const uint4*)&lb[lane & 15][kc * 32 + ((lane >> 4) & 3) * 8];
    }
}

// ---------------------------------------------------------------------------
// K1: qp[b][n] = sum_h query[b][h]*Wa_w[n][h] + Wa_b[n] + Ua_b[n]
__global__ __launch_bounds__(256) void k1_qproj(
    const float* __restrict__ q, const float* __restrict__ Wa,
    const float* __restrict__ Wab, const float* __restrict__ Uab,
    float* __restrict__ qp) {
    int b = blockIdx.y;
    int t = threadIdx.x;
    int n = blockIdx.x * 64 + (t >> 2);
    int quarter = t & 3;
    __shared__ float qs[H];
    for (int i = t; i < H; i += 256) qs[i] = q[b * H + i];
    __syncthreads();
    const float4* wr = (const float4*)(Wa + (size_t)n * H + quarter * 256);
    const float* qq = qs + quarter * 256;
    float acc = 0.f;
#pragma unroll 4
    for (int i = 0; i < 64; i++) {
        float4 w = wr[i];
        acc += qq[i * 4 + 0] * w.x + qq[i * 4 + 1] * w.y +
               qq[i * 4 + 2] * w.z + qq[i * 4 + 3] * w.w;
    }
    acc += __shfl_xor(acc, 1, 64);
    acc += __shfl_xor(acc, 2, 64);
    if (quarter == 0) qp[b * H + n] = acc + Wab[n] + Uab[n];
}

// ---------------------------------------------------------------------------
// K2v7: 256x256-tile, 8-wave (2M x 4N), BK=64, 4-phase-per-K-tile schedule
// (port of the proven 8-phase/2-K-tile template). Per-wave C = 128x64
// (acc[8][4] f32x4 = 128 AGPR); live frags A[4][2]+B[4][2] = 64 VGPR.
// LDS = 2 buffers x (A 32KB + B 32KB) = 128 KB dynamic. Both operands staged
// via global_load_lds in half-tiles (16 KB, 2 loads/thread). Phases:
//  ph1: ds A(mf0-3) + B(nf0-1) | BAR | lgkm0 | 16 MFMA | BAR
//  ph2: ds B(nf2-3)            | BAR | lgkm0 | 16 MFMA | BAR
//  ph3: ds A(mf4-7) + stage B(kt+2) | BAR | lgkm0 | 16 MFMA | BAR
//  ph4: stage A(kt+2)          | BAR |         16 MFMA | vmcnt(8) BAR
// Write-safety: B of buf d fully consumed by ph2-end barrier (stage at ph3);
// A consumed by ph3-end barrier (stage at ph4). vmcnt(8) at the K-tile
// boundary retires tile kt+1's 8 loads (issued 1 tile ago) and leaves tile
// kt+2's 8 in flight -- never vmcnt(0) in-loop. sched_barrier(0) fences every
// barrier so the compiler cannot hoist ds/stage ops across phases.
__global__ __launch_bounds__(512, 2) void k2_scores7(
    const uint4* __restrict__ Abf, const uint4* __restrict__ UaSw,
    const float* __restrict__ qp, const float* __restrict__ Vaw,
    float* __restrict__ sp) {
    extern __shared__ uint4 lds[];            // 8192 uint4 = 128 KB
    const int tid = threadIdx.x;
    const int lane = tid & 63;
    const int w = tid >> 6;                   // 0..7
    const int wm = w >> 2;                    // 0..1  (M half)
    const int wn = w & 3;                     // 0..3  (N quarter)
    const int lid = blockIdx.x;               // 0..1023
    const int c = lid & 7;                    // XCD slot
    const int q = lid >> 3;                   // 0..127
    const int nblk = q & 3;                   // 256-col block
    const int mi = (q >> 2) * 8 + c;          // 0..255 (256-row block)
    const int b = mi >> 3;

    const uint4* pag = Abf + (size_t)(mi * 16) * 2048;        // stile-major
    const uint4* pbg = UaSw + (size_t)(nblk * 2) * 16384;     // nb-major

    f32x4 acc[8][4];
#pragma unroll
    for (int m = 0; m < 8; m++)
#pragma unroll
        for (int n = 0; n < 4; n++) acc[m][n] = (f32x4){0.f, 0.f, 0.f, 0.f};

    // LDS map (uint4 idx, buffer base dofs = (kt&1)*4096):
    //  A: dofs + (strel*2 + kcr)*64 + lane          (strel 0..15, kcr 0..1)
    //  B: dofs + 2048 + (nbrel*2 + kcr)*512 + nt*64 + lane
    auto STAGE_A = [&](int kt, int dofs, int h) {   // half h: strel h*8..h*8+7
#pragma unroll
        for (int i = 0; i < 2; i++) {
            int cc = w * 2 + i;                      // 0..15
            int strel = h * 8 + (cc >> 1);
            int kcr = cc & 1;
            async_copy16(pag + ((size_t)strel * 32 + (kt * 2 + kcr)) * 64 + lane,
                         (void*)&lds[dofs + (strel * 2 + kcr) * 64 + lane]);
        }
    };
    auto STAGE_B = [&](int kt, int dofs, int h) {   // half h: nbrel = h
#pragma unroll
        for (int i = 0; i < 2; i++) {
            int cc = w * 2 + i;                      // 0..15
            int kcr = cc >> 3;
            int nt = cc & 7;
            async_copy16(pbg + (size_t)h * 16384 + (size_t)(kt * 2 + kcr) * 512 +
                             nt * 64 + lane,
                         (void*)&lds[dofs + 2048 + (h * 2 + kcr) * 512 + nt * 64 + lane]);
        }
    };

    // prologue: stage tiles 0 (buf0) and 1 (buf1): 16 loads; vmcnt(8) -> tile0 landed
    STAGE_A(0, 0, 0); STAGE_A(0, 0, 1); STAGE_B(0, 0, 0); STAGE_B(0, 0, 1);
    __builtin_amdgcn_sched_barrier(0);
    STAGE_A(1, 4096, 0); STAGE_A(1, 4096, 1); STAGE_B(1, 4096, 0); STAGE_B(1, 4096, 1);
    __builtin_amdgcn_sched_barrier(0);
    asm volatile("s_waitcnt vmcnt(8)" ::: "memory");
    BAR();

    const int nbr = wn >> 1;                  // this wave's B half
    const int ntb = (wn & 1) * 4;             // nt base within half

    for (int kt = 0; kt < 16; ++kt) {
        const int dofs = (kt & 1) << 12;      // *4096
        const int kn = (kt + 2) & 15;         // prefetch target (tail: redundant)
        U4 af[4][2], bf[4][2];

        // ---- phase 1: A mf0-3 + B nf0-1
#pragma unroll
        for (int m = 0; m < 4; m++)
#pragma unroll
            for (int k = 0; k < 2; k++)
                af[m][k].u = lds[dofs + ((wm * 8 + m) * 2 + k) * 64 + lane];
#pragma unroll
        for (int n = 0; n < 2; n++)
#pragma unroll
            for (int k = 0; k < 2; k++)
                bf[n][k].u = lds[dofs + 2048 + (nbr * 2 + k) * 512 + (ntb + n) * 64 + lane];
        BAR();
        asm volatile("s_waitcnt lgkmcnt(0)" ::: "memory");
        __builtin_amdgcn_sched_barrier(0);
        __builtin_amdgcn_s_setprio(1);
#pragma unroll
        for (int m = 0; m < 4; m++)
#pragma unroll
            for (int n = 0; n < 2; n++)
#pragma unroll
                for (int k = 0; k < 2; k++)
                    acc[m][n] = __builtin_amdgcn_mfma_f32_16x16x32_bf16(
                        af[m][k].b, bf[n][k].b, acc[m][n], 0, 0, 0);
        __builtin_amdgcn_s_setprio(0);
        BAR();

        // ---- phase 2: B nf2-3
#pragma unroll
        for (int n = 0; n < 2; n++)
#pragma unroll
            for (int k = 0; k < 2; k++)
                bf[2 + n][k].u = lds[dofs + 2048 + (nbr * 2 + k) * 512 + (ntb + 2 + n) * 64 + lane];
        BAR();
        asm volatile("s_waitcnt lgkmcnt(0)" ::: "memory");
        __builtin_amdgcn_sched_barrier(0);
        __builtin_amdgcn_s_setprio(1);
#pragma unroll
        for (int m = 0; m < 4; m++)
#pragma unroll
            for (int n = 0; n < 2; n++)
#pragma unroll
                for (int k = 0; k < 2; k++)
                    acc[m][2 + n] = __builtin_amdgcn_mfma_f32_16x16x32_bf16(
                        af[m][k].b, bf[2 + n][k].b, acc[m][2 + n], 0, 0, 0);
        __builtin_amdgcn_s_setprio(0);
        BAR();

        // ---- phase 3: A mf4-7 ; stage B(kt+2) into this buffer (B consumed)
#pragma unroll
        for (int m = 0; m < 4; m++)
#pragma unroll
            for (int k = 0; k < 2; k++)
                af[m][k].u = lds[dofs + ((wm * 8 + 4 + m) * 2 + k) * 64 + lane];
        STAGE_B(kn, dofs, 0);
        STAGE_B(kn, dofs, 1);
        BAR();
        asm volatile("s_waitcnt lgkmcnt(0)" ::: "memory");
        __builtin_amdgcn_sched_barrier(0);
        __builtin_amdgcn_s_setprio(1);
#pragma unroll
        for (int m = 0; m < 4; m++)
#pragma unroll
            for (int n = 0; n < 2; n++)
#pragma unroll
                for (int k = 0; k < 2; k++)
                    acc[4 + m][n] = __builtin_amdgcn_mfma_f32_16x16x32_bf16(
                        af[m][k].b, bf[n][k].b, acc[4 + m][n], 0, 0, 0);
        __builtin_amdgcn_s_setprio(0);
        BAR();

        // ---- phase 4: stage A(kt+2) (A consumed); MFMA acc[4+m][2+n]
        STAGE_A(kn, dofs, 0);
        STAGE_A(kn, dofs, 1);
        BAR();
        __builtin_amdgcn_s_setprio(1);
#pragma unroll
        for (int m = 0; m < 4; m++)
#pragma unroll
            for (int n = 0; n < 2; n++)
#pragma unroll
                for (int k = 0; k < 2; k++)
                    acc[4 + m][2 + n] = __builtin_amdgcn_mfma_f32_16x16x32_bf16(
                        af[m][k].b, bf[2 + n][k].b, acc[4 + m][2 + n], 0, 0, 0);
        __builtin_amdgcn_s_setprio(0);
        // K-tile boundary: retire tile kt+1's 8 loads, keep kt+2's 8 in flight
        __builtin_amdgcn_sched_barrier(0);
        asm volatile("s_waitcnt vmcnt(8)" ::: "memory");
        BAR();
    }
    asm volatile("s_waitcnt vmcnt(0)" ::: "memory");   // drain tail stages

    // epilogue: tanh + dot Va + 16-lane col reduce; plane = nblk*4 + wn
    const int col = lane & 15, qd = lane >> 4;
    float qv[4], vv[4];
#pragma unroll
    for (int nf = 0; nf < 4; nf++) {
        int n = nblk * 256 + (wn * 4 + nf) * 16 + col;
        qv[nf] = qp[b * H + n];
        vv[nf] = Vaw[n];
    }
    const int plane = nblk * 4 + wn;
#pragma unroll
    for (int mf = 0; mf < 8; mf++) {
        float rs[4] = {0.f, 0.f, 0.f, 0.f};
#pragma unroll
        for (int nf = 0; nf < 4; nf++)
#pragma unroll
            for (int r = 0; r < 4; r++)
                rs[r] += ftanh(acc[mf][nf][r] + qv[nf]) * vv[nf];
#pragma unroll
        for (int r = 0; r < 4; r++) {
            float v = rs[r];
            v += __shfl_xor(v, 1, 64);
            v += __shfl_xor(v, 2, 64);
            v += __shfl_xor(v, 4, 64);
            v += __shfl_xor(v, 8, 64);
            if (col == 0)
                sp[(size_t)plane * (B * S) + mi * 256 + wm * 128 + mf * 16 + qd * 4 + r] = v;
        }
    }
}

// ---------------------------------------------------------------------------
// K4v3: fused partial-sum (16 planes) + softmax + weights-write + context.
// grid (8,32): block (kcg,b); wave wv handles kc=kcg*4+wv.
__global__ __launch_bounds__(256) void k4_ctx2(const uint4* __restrict__ Abf,
                                               const float* __restrict__ sp,
                                               float* __restrict__ out) {
    int kcg = blockIdx.x, b = blockIdx.y;
    int t = threadIdx.x;
    __shared__ float red[256];
    __shared__ float wl[S];   // 8 KB

    float v[8];
#pragma unroll
    for (int i = 0; i < 8; i++) {
        int s = i * 256 + t;
        float sum = 0.f;
#pragma unroll
        for (int nb = 0; nb < 16; nb++) sum += sp[(size_t)nb * B * S + b * S + s];
        v[i] = sum;
    }
    float lm = -1e30f;
#pragma unroll
    for (int i = 0; i < 8; i++) lm = fmaxf(lm, v[i]);
    red[t] = lm;
    __syncthreads();
    for (int s = 128; s > 0; s >>= 1) {
        if (t < s) red[t] = fmaxf(red[t], red[t + s]);
        __syncthreads();
    }
    float m = red[0];
    __syncthreads();
    float ls = 0.f;
#pragma unroll
    for (int i = 0; i < 8; i++) ls += __expf(v[i] - m);
    red[t] = ls;
    __syncthreads();
    for (int s = 128; s > 0; s >>= 1) {
        if (t < s) red[t] += red[t + s];
        __syncthreads();
    }
    float inv = 1.f / red[0];
#pragma unroll
    for (int i = 0; i < 8; i++) {
        int s = i * 256 + t;
        float w = __expf(v[i] - m) * inv;
        wl[s] = w;
        if (kcg == 0) out[B * H + b * S + s] = w;
    }
    __syncthreads();

    const int wv = t >> 6, lane = t & 63, qd = lane >> 4, colr = lane & 15;
    const int kc = kcg * 4 + wv;
    float a8[8] = {0.f, 0.f, 0.f, 0.f, 0.f, 0.f, 0.f, 0.f};
    const uint4* base = Abf + ((size_t)(b * 128) * 32 + kc) * 64 + lane;
#pragma unroll 4
    for (int st = 0; st < 128; st++) {
        uint4 f = base[(size_t)st * 2048];
        float w = wl[st * 16 + colr];
        a8[0] += w * __uint_as_float(f.x << 16);
        a8[1] += w * __uint_as_float(f.x & 0xffff0000u);
        a8[2] += w * __uint_as_float(f.y << 16);
        a8[3] += w * __uint_as_float(f.y & 0xffff0000u);
        a8[4] += w * __uint_as_float(f.z << 16);
        a8[5] += w * __uint_as_float(f.z & 0xffff0000u);
        a8[6] += w * __uint_as_float(f.w << 16);
        a8[7] += w * __uint_as_float(f.w & 0xffff0000u);
    }
#pragma unroll
    for (int j = 0; j < 8; j++) {
        float vj = a8[j];
        vj += __shfl_xor(vj, 1, 64);
        vj += __shfl_xor(vj, 2, 64);
        vj += __shfl_xor(vj, 4, 64);
        vj += __shfl_xor(vj, 8, 64);
        a8[j] = vj;
    }
    if (colr == 0) {
        int colbase = kc * 32 + qd * 8;
#pragma unroll
        for (int j = 0; j < 8; j++) out[b * H + colbase + j] = a8[j];
    }
}

// ===========================================================================
// Fallback path (ws too small): round-4 kernels (8 partial planes)
// ===========================================================================
__global__ __launch_bounds__(256, 3) void k2_scores_fb(
    const float* __restrict__ keys, const uint4* __restrict__ UaSw,
    const float* __restrict__ qp, const float* __restrict__ Vaw,
    float* __restrict__ sp) {
    __shared__ uint4 As[2][512];
    __shared__ uint4 Bs[2][512];
    __shared__ float part[2][128];
    const int tid = threadIdx.x;
    const int lane = tid & 63;
    const int wave = tid >> 6;
    const int wm = wave >> 1, wn = wave & 1;
    const int lid = blockIdx.x;
    const int c = lid & 7;
    const int qq = lid >> 3;
    const int nb = qq & 7;
    const int mb = (qq >> 3) * 8 + c;
    const int b = mb >> 4;
    const int s0 = (mb & 15) << 7;
    const int el = tid & 63;
    const int srow0 = s0 + (tid >> 6) * 16 + (el & 15);
    const int srow1 = srow0 + 64;
    const int kofs = ((el >> 4) & 3) * 8;
    const float4* ka0 = (const float4*)(keys + ((size_t)b * S + srow0) * H + kofs);
    const float4* ka1 = (const float4*)(keys + ((size_t)b * S + srow1) * H + kofs);
    const uint4* srcB = UaSw + (size_t)nb * 32 * 512;
    f32x4 acc[4][4];
#pragma unroll
    for (int mt = 0; mt < 4; mt++)
#pragma unroll
        for (int nt = 0; nt < 4; nt++) acc[mt][nt] = (f32x4){0.f, 0.f, 0.f, 0.f};
    float4 x0 = ka0[0], y0 = ka0[1], x1 = ka1[0], y1 = ka1[1];
    async_copy16(srcB + tid,       &Bs[0][tid]);
    async_copy16(srcB + tid + 256, &Bs[0][tid + 256]);
    As[0][tid]       = pack8(x0, y0);
    As[0][tid + 256] = pack8(x1, y1);
    x0 = ka0[8]; y0 = ka0[9]; x1 = ka1[8]; y1 = ka1[9];
    __syncthreads();
    for (int kc = 0; kc < 32; kc++) {
        const int cur = kc & 1, nxt = cur ^ 1;
        if (kc < 31) {
            async_copy16(srcB + (size_t)(kc + 1) * 512 + tid,       &Bs[nxt][tid]);
            async_copy16(srcB + (size_t)(kc + 1) * 512 + tid + 256, &Bs[nxt][tid + 256]);
            As[nxt][tid]       = pack8(x0, y0);
            As[nxt][tid + 256] = pack8(x1, y1);
            if (kc < 30) {
                x0 = ka0[(kc + 2) * 8]; y0 = ka0[(kc + 2) * 8 + 1];
                x1 = ka1[(kc + 2) * 8]; y1 = ka1[(kc + 2) * 8 + 1];
            }
        }
        U4 af[4], bf[4];
#pragma unroll
        for (int mt = 0; mt < 4; mt++) af[mt].u = As[cur][(wm * 4 + mt) * 64 + lane];
#pragma unroll
        for (int nt = 0; nt < 4; nt++) bf[nt].u = Bs[cur][(wn * 4 + nt) * 64 + lane];
#pragma unroll
        for (int mt = 0; mt < 4; mt++)
#pragma unroll
            for (int nt = 0; nt < 4; nt++)
                acc[mt][nt] = __builtin_amdgcn_mfma_f32_16x16x32_bf16(
                    af[mt].b, bf[nt].b, acc[mt][nt], 0, 0, 0);
        __syncthreads();
    }
    const int col = lane & 15, qd = lane >> 4;
    float qv[4], vv[4];
#pragma unroll
    for (int nt = 0; nt < 4; nt++) {
        int n = nb * 128 + (wn * 4 + nt) * 16 + col;
        qv[nt] = qp[b * H + n];
        vv[nt] = Vaw[n];
    }
#pragma unroll
    for (int mt = 0; mt < 4; mt++) {
        float rs[4] = {0.f, 0.f, 0.f, 0.f};
#pragma unroll
        for (int nt = 0; nt < 4; nt++)
#pragma unroll
            for (int r = 0; r < 4; r++)
                rs[r] += ftanh(acc[mt][nt][r] + qv[nt]) * vv[nt];
#pragma unroll
        for (int r = 0; r < 4; r++) {
            float v = rs[r];
            v += __shfl_xor(v, 1, 64);
            v += __shfl_xor(v, 2, 64);
            v += __shfl_xor(v, 4, 64);
            v += __shfl_xor(v, 8, 64);
            if (col == 0) part[wn][wm * 64 + mt * 16 + qd * 4 + r] = v;
        }
    }
    __syncthreads();
    if (tid < 128)
        sp[(size_t)nb * B * S + b * S + s0 + tid] = part[0][tid] + part[1][tid];
}

__global__ __launch_bounds__(256) void k4_ctx_fb(const float* __restrict__ keys,
                                                 const float* __restrict__ sp,
                                                 float* __restrict__ out) {
    int sc = blockIdx.x, b = blockIdx.y;
    int t = threadIdx.x;
    __shared__ float red[256];
    __shared__ float wl[64];
    float v[8];
#pragma unroll
    for (int i = 0; i < 8; i++) {
        int s = i * 256 + t;
        float sum = 0.f;
#pragma unroll
        for (int nb = 0; nb < 8; nb++) sum += sp[(size_t)nb * B * S + b * S + s];
        v[i] = sum;
    }
    float lm = -1e30f;
#pragma unroll
    for (int i = 0; i < 8; i++) lm = fmaxf(lm, v[i]);
    red[t] = lm;
    __syncthreads();
    for (int s = 128; s > 0; s >>= 1) {
        if (t < s) red[t] = fmaxf(red[t], red[t + s]);
        __syncthreads();
    }
    float m = red[0];
    __syncthreads();
    float ls = 0.f;
#pragma unroll
    for (int i = 0; i < 8; i++) ls += __expf(v[i] - m);
    red[t] = ls;
    __syncthreads();
    for (int s = 128; s > 0; s >>= 1) {
        if (t < s) red[t] += red[t + s];
        __syncthreads();
    }
    float inv = 1.f / red[0];
    if (t < 64) {
        int s = sc * 64 + t;
        float sum = 0.f;
#pragma unroll
        for (int nb = 0; nb < 8; nb++) sum += sp[(size_t)nb * B * S + b * S + s];
        float w = __expf(sum - m) * inv;
        wl[t] = w;
        out[B * H + b * S + s] = w;
    }
    __syncthreads();
    const float4* kp = (const float4*)(keys + ((size_t)b * S + sc * 64) * H) + t;
    float4 acc = {0.f, 0.f, 0.f, 0.f};
#pragma unroll 8
    for (int s = 0; s < 64; s++) {
        float4 kv = kp[(size_t)s * 256];
        float w = wl[s];
        acc.x += w * kv.x; acc.y += w * kv.y;
        acc.z += w * kv.z; acc.w += w * kv.w;
    }
    float* dst = out + b * H + t * 4;
    atomicAdd(dst + 0, acc.x);
    atomicAdd(dst + 1, acc.y);
    atomicAdd(dst + 2, acc.z);
    atomicAdd(dst + 3, acc.w);
}

// ---------------------------------------------------------------------------
extern "C" void kernel_launch(void* const* d_in, const int* in_sizes, int n_in,
                              void* d_out, int out_size, void* d_ws, size_t ws_size,
                              hipStream_t stream) {
    const float* query = (const float*)d_in[0];
    const float* keys  = (const float*)d_in[1];
    const float* Wa_w  = (const float*)d_in[2];
    const float* Wa_b  = (const float*)d_in[3];
    const float* Ua_w  = (const float*)d_in[4];
    const float* Ua_b  = (const float*)d_in[5];
    const float* Va_w  = (const float*)d_in[6];
    float* out = (float*)d_out;

    // ws: [0,2MB) UaSw; [2MB,+128KB) qp; [2MB+128KB,+4MB) sp(16 planes); [8MB,+128MB) Abf
    uint4* UaSw = (uint4*)d_ws;
    float* qp = (float*)((char*)d_ws + (2u << 20));
    float* sp = (float*)((char*)d_ws + (2u << 20) + (128u << 10));
    uint4* Abf = (uint4*)((char*)d_ws + (8u << 20));
    const size_t NEED = (size_t)(8u << 20) + ((size_t)128u << 20);

    if (ws_size >= NEED) {
        static bool inited = false;
        if (!inited) {
            hipFuncSetAttribute(reinterpret_cast<const void*>(k2_scores7),
                                hipFuncAttributeMaxDynamicSharedMemorySize, 131072);
            inited = true;
        }
        ka_swz2<<<4096, 256, 0, stream>>>(keys, Abf);
        k0_swizzle<<<512, 256, 0, stream>>>(Ua_w, UaSw);
        k1_qproj<<<dim3(16, B), 256, 0, stream>>>(query, Wa_w, Wa_b, Ua_b, qp);
        k2_scores7<<<1024, 512, 131072, stream>>>(Abf, UaSw, qp, Va_w, sp);
        k4_ctx2<<<dim3(8, B), 256, 0, stream>>>(Abf, sp, out);
    } else {
        hipMemsetAsync(d_out, 0, B * H * sizeof(float), stream);
        k0_swizzle<<<512, 256, 0, stream>>>(Ua_w, UaSw);
        k1_qproj<<<dim3(16, B), 256, 0, stream>>>(query, Wa_w, Wa_b, Ua_b, qp);
        k2_scores_fb<<<4096, 256, 0, stream>>>(keys, UaSw, qp, Va_w, sp);
        k4_ctx_fb<<<dim3(32, B), 256, 0, stream>>>(keys, sp, out);
    }
}

// Round 6
// 570.014 us; speedup vs baseline: 1.0339x; 1.0300x over previous
//
#include <hip/hip_runtime.h>
#include <hip/hip_bf16.h>

#define H 1024
#define B 32
#define S 2048

typedef __attribute__((ext_vector_type(8))) short bf16x8;
typedef __attribute__((ext_vector_type(4))) float f32x4;

union U4 { uint4 u; bf16x8 b; };

__device__ __forceinline__ unsigned short f2bf(float f) {
    unsigned u = __float_as_uint(f);
    unsigned r = (u + 0x7fffu + ((u >> 16) & 1u)) >> 16;
    return (unsigned short)r;
}

__device__ __forceinline__ uint4 pack8(float4 x, float4 y) {
    uint4 p;
    p.x = (unsigned)f2bf(x.x) | ((unsigned)f2bf(x.y) << 16);
    p.y = (unsigned)f2bf(x.z) | ((unsigned)f2bf(x.w) << 16);
    p.z = (unsigned)f2bf(y.x) | ((unsigned)f2bf(y.y) << 16);
    p.w = (unsigned)f2bf(y.z) | ((unsigned)f2bf(y.w) << 16);
    return p;
}

__device__ __forceinline__ float ftanh(float x) {
    float x2 = __builtin_amdgcn_fmed3f(x + x, -30.f, 30.f);
    float e = __expf(x2);
    return 1.f - 2.f * __builtin_amdgcn_rcpf(e + 1.f);
}

__device__ __forceinline__ void async_copy16(const void* g, void* l) {
    __builtin_amdgcn_global_load_lds(
        (const __attribute__((address_space(1))) unsigned int*)g,
        (__attribute__((address_space(3))) unsigned int*)l, 16, 0, 0);
}

// ---------------------------------------------------------------------------
// K0: Ua_w fp32 [n][k] -> bf16 MFMA-B-frag order: UaSw[nb(8)][kc(32)][nt(8)*64+lane]
__global__ void k0_swizzle(const float* __restrict__ Ua, uint4* __restrict__ UaSw) {
    int t = blockIdx.x * 256 + threadIdx.x;   // 0..131071
    int lane = t & 63;
    int nt = (t >> 6) & 7;
    int kc = (t >> 9) & 31;
    int nb = t >> 14;
    int n = nb * 128 + nt * 16 + (lane & 15);
    int k = kc * 32 + ((lane >> 4) & 3) * 8;
    const float4* src = (const float4*)(Ua + (size_t)n * H + k);
    UaSw[t] = pack8(src[0], src[1]);
}

// ---------------------------------------------------------------------------
// KA2: keys fp32 -> bf16 MFMA A-frag order via LDS transpose (both global
// sides coalesced).
__global__ __launch_bounds__(256) void ka_swz2(const float* __restrict__ keys,
                                               uint4* __restrict__ Abf) {
    __shared__ unsigned short lb[16][1032];   // 33 KB
    const int t = threadIdx.x;
    const size_t blk = blockIdx.x;            // 0..4095 (stile)
    const float4* src = (const float4*)keys + blk * 4096;   // 16 rows x 256 f4
#pragma unroll
    for (int i = 0; i < 16; ++i) {
        int f = i * 256 + t;                  // 0..4095
        float4 v = src[f];
        int row = f >> 8;
        int c4 = (f & 255) << 2;
        uint2 pk;
        pk.x = (unsigned)f2bf(v.x) | ((unsigned)f2bf(v.y) << 16);
        pk.y = (unsigned)f2bf(v.z) | ((unsigned)f2bf(v.w) << 16);
        *(uint2*)&lb[row][c4] = pk;
    }
    __syncthreads();
    uint4* dst = Abf + blk * 2048;
#pragma unroll
    for (int i = 0; i < 8; ++i) {
        int cidx = i * 256 + t;               // 0..2047 = kc*64 + lane
        int lane = cidx & 63;
        int kc = cidx >> 6;
        dst[cidx] = *(const uint4*)&lb[lane & 15][kc * 32 + ((lane >> 4) & 3) * 8];
    }
}

// ---------------------------------------------------------------------------
// K1v2: qp[b][n] = sum_h q[b][h]*Wa[n][h] + Wab[n] + Uab[n].
// Coalesced: each wave owns 16 n-rows sequentially; per n the wave reads the
// full 4KB row as 4 contiguous 1KB wave-loads (was: 16B granules scattered
// across 16 rows per wave-load). q staged in LDS, read as float4 (hoisted).
__global__ __launch_bounds__(256) void k1_qproj(
    const float* __restrict__ q, const float* __restrict__ Wa,
    const float* __restrict__ Wab, const float* __restrict__ Uab,
    float* __restrict__ qp) {
    int b = blockIdx.y;
    int t = threadIdx.x;
    int wave = t >> 6, lane = t & 63;
    __shared__ float qs[H];
    for (int i = t; i < H; i += 256) qs[i] = q[b * H + i];
    __syncthreads();
    float4 qv[4];
#pragma unroll
    for (int i = 0; i < 4; ++i) qv[i] = *(const float4*)(qs + i * 256 + lane * 4);
#pragma unroll 2
    for (int j = 0; j < 16; ++j) {
        int n = blockIdx.x * 64 + wave * 16 + j;
        const float4* wr = (const float4*)(Wa + (size_t)n * H) + lane;
        float acc = 0.f;
#pragma unroll
        for (int i = 0; i < 4; ++i) {
            float4 w = wr[i * 64];
            acc += qv[i].x * w.x + qv[i].y * w.y + qv[i].z * w.z + qv[i].w * w.w;
        }
        acc += __shfl_xor(acc, 1, 64);
        acc += __shfl_xor(acc, 2, 64);
        acc += __shfl_xor(acc, 4, 64);
        acc += __shfl_xor(acc, 8, 64);
        acc += __shfl_xor(acc, 16, 64);
        acc += __shfl_xor(acc, 32, 64);
        if (lane == 0) qp[b * H + n] = acc + Wab[n] + Uab[n];
    }
}

// ---------------------------------------------------------------------------
// K2v9: R3 structure (best: 170us) with 2 kc per step -> sync tax halved.
// Block = 128 rows x 128 n, 4 waves, wave wm owns 2 m-tiles x 8 n-tiles
// (acc 2x8 f32x4 = 64 AGPR, proven). B staged via global_load_lds, 16 KB per
// step (kc pair), 3 buffers (48 KB, 3 blk/CU), distance 2. A = bf16 register
// stream from Abf, 4 loads/step, 1 step (=2 kc) ahead. Per step: 32 MFMA,
// 16 ds_read_b128, ONE boundary {sched_barrier; vmcnt(4); s_barrier} -- 16
// sync events instead of 32. Invariant: <=4 loads outstanding cross each
// barrier and they are never the next-read tile (holds for either VMEM issue
// order of A vs B within a step; the ca=na copy's implicit wait drains A).
__global__ __launch_bounds__(256, 3) void k2_scores9(
    const uint4* __restrict__ Abf, const uint4* __restrict__ UaSw,
    const float* __restrict__ qp, const float* __restrict__ Vaw,
    float* __restrict__ sp) {
    __shared__ uint4 bbuf[3][1024];   // 48 KB
    const int tid = threadIdx.x;
    const int lane = tid & 63;
    const int wm = tid >> 6;
    const int lid = blockIdx.x;      // 0..4095
    const int c = lid & 7;           // XCD slot
    const int qq = lid >> 3;
    const int nb = qq & 7;           // nb cycles fastest within an XCD
    const int mb = (qq >> 3) * 8 + c;
    const int b = mb >> 4;
    const int s0 = (mb & 15) << 7;

    const int stile0 = mb * 8 + wm * 2;
    const uint4* pa = Abf + (size_t)stile0 * 2048 + lane;   // kc stride 64, mt stride 2048
    const uint4* pbg = UaSw + (size_t)nb * 16384;           // kc stride 512

    f32x4 acc[2][8];
#pragma unroll
    for (int mt = 0; mt < 2; mt++)
#pragma unroll
        for (int nt = 0; nt < 8; nt++) acc[mt][nt] = (f32x4){0.f, 0.f, 0.f, 0.f};

    // prologue: A step0 (kc0,1) 4 loads; B step0 -> buf0, step1 -> buf1.
    U4 ca[2][2];
    ca[0][0].u = pa[0];
    ca[1][0].u = pa[2048];
    ca[0][1].u = pa[64];
    ca[1][1].u = pa[2048 + 64];
    async_copy16(pbg + tid,        &bbuf[0][tid]);
    async_copy16(pbg + 256 + tid,  &bbuf[0][tid + 256]);
    async_copy16(pbg + 512 + tid,  &bbuf[0][tid + 512]);
    async_copy16(pbg + 768 + tid,  &bbuf[0][tid + 768]);
    async_copy16(pbg + 1024 + tid, &bbuf[1][tid]);
    async_copy16(pbg + 1280 + tid, &bbuf[1][tid + 256]);
    async_copy16(pbg + 1536 + tid, &bbuf[1][tid + 512]);
    async_copy16(pbg + 1792 + tid, &bbuf[1][tid + 768]);
    __builtin_amdgcn_sched_barrier(0);
    asm volatile("s_waitcnt vmcnt(4)" ::: "memory");   // A(0)+B(0) landed; B(1) in flight
    __builtin_amdgcn_s_barrier();
    __builtin_amdgcn_sched_barrier(0);

    int cb = 0, tb = 2;
#pragma unroll 4
    for (int s = 0; s < 16; ++s) {
        // A prefetch for step s+1 (kc 2s+2, 2s+3); tail wraps (redundant)
        const int sn = (s + 1) & 15;
        U4 na[2][2];
        na[0][0].u = pa[(2 * sn) * 64];
        na[1][0].u = pa[(2 * sn) * 64 + 2048];
        na[0][1].u = pa[(2 * sn + 1) * 64];
        na[1][1].u = pa[(2 * sn + 1) * 64 + 2048];

        // B stage for step s+2 into buf tb (== buf read at step s-1: safe)
        const int ts = (s + 2) & 15;
        const uint4* bsrc = pbg + (size_t)ts * 1024;
        async_copy16(bsrc + tid,       &bbuf[tb][tid]);
        async_copy16(bsrc + 256 + tid, &bbuf[tb][tid + 256]);
        async_copy16(bsrc + 512 + tid, &bbuf[tb][tid + 512]);
        async_copy16(bsrc + 768 + tid, &bbuf[tb][tid + 768]);

        // kc0 of this step
        U4 bb[8];
#pragma unroll
        for (int nt = 0; nt < 8; nt++) bb[nt].u = bbuf[cb][nt * 64 + lane];
        __builtin_amdgcn_s_setprio(1);
#pragma unroll
        for (int nt = 0; nt < 8; nt++)
#pragma unroll
            for (int mt = 0; mt < 2; mt++)
                acc[mt][nt] = __builtin_amdgcn_mfma_f32_16x16x32_bf16(
                    ca[mt][0].b, bb[nt].b, acc[mt][nt], 0, 0, 0);
        __builtin_amdgcn_s_setprio(0);
        // kc1 of this step
#pragma unroll
        for (int nt = 0; nt < 8; nt++) bb[nt].u = bbuf[cb][512 + nt * 64 + lane];
        __builtin_amdgcn_s_setprio(1);
#pragma unroll
        for (int nt = 0; nt < 8; nt++)
#pragma unroll
            for (int mt = 0; mt < 2; mt++)
                acc[mt][nt] = __builtin_amdgcn_mfma_f32_16x16x32_bf16(
                    ca[mt][1].b, bb[nt].b, acc[mt][nt], 0, 0, 0);
        __builtin_amdgcn_s_setprio(0);

        ca[0][0] = na[0][0]; ca[1][0] = na[1][0];   // implicit wait drains A(s+1)
        ca[0][1] = na[0][1]; ca[1][1] = na[1][1];

        // boundary: B(s+1) guaranteed landed; <=4 newest (B stage s+2) in flight
        __builtin_amdgcn_sched_barrier(0);
        asm volatile("s_waitcnt vmcnt(4)" ::: "memory");
        __builtin_amdgcn_s_barrier();
        __builtin_amdgcn_sched_barrier(0);

        cb = (cb == 2) ? 0 : cb + 1;
        tb = (tb == 2) ? 0 : tb + 1;
    }
    asm volatile("s_waitcnt vmcnt(0)" ::: "memory");   // drain tail stages

    // epilogue: tanh, dot Va, shfl-reduce over col(16), direct store
    const int col = lane & 15, qd = lane >> 4;
    float qv[8], vv[8];
#pragma unroll
    for (int nt = 0; nt < 8; nt++) {
        int n = nb * 128 + nt * 16 + col;
        qv[nt] = qp[b * H + n];
        vv[nt] = Vaw[n];
    }
#pragma unroll
    for (int mt = 0; mt < 2; mt++) {
        float rs[4] = {0.f, 0.f, 0.f, 0.f};
#pragma unroll
        for (int nt = 0; nt < 8; nt++)
#pragma unroll
            for (int r = 0; r < 4; r++)
                rs[r] += ftanh(acc[mt][nt][r] + qv[nt]) * vv[nt];
#pragma unroll
        for (int r = 0; r < 4; r++) {
            float v = rs[r];
            v += __shfl_xor(v, 1, 64);
            v += __shfl_xor(v, 2, 64);
            v += __shfl_xor(v, 4, 64);
            v += __shfl_xor(v, 8, 64);
            if (col == 0)
                sp[(size_t)nb * B * S + b * S + s0 + wm * 32 + mt * 16 + qd * 4 + r] = v;
        }
    }
}

// ---------------------------------------------------------------------------
// K4v2: fused partial-sum (8 planes) + softmax + weights-write + context.
__global__ __launch_bounds__(256) void k4_ctx2(const uint4* __restrict__ Abf,
                                               const float* __restrict__ sp,
                                               float* __restrict__ out) {
    int kcg = blockIdx.x, b = blockIdx.y;
    int t = threadIdx.x;
    __shared__ float red[256];
    __shared__ float wl[S];   // 8 KB

    float v[8];
#pragma unroll
    for (int i = 0; i < 8; i++) {
        int s = i * 256 + t;
        float sum = 0.f;
#pragma unroll
        for (int nb = 0; nb < 8; nb++) sum += sp[(size_t)nb * B * S + b * S + s];
        v[i] = sum;
    }
    float lm = -1e30f;
#pragma unroll
    for (int i = 0; i < 8; i++) lm = fmaxf(lm, v[i]);
    red[t] = lm;
    __syncthreads();
    for (int s = 128; s > 0; s >>= 1) {
        if (t < s) red[t] = fmaxf(red[t], red[t + s]);
        __syncthreads();
    }
    float m = red[0];
    __syncthreads();
    float ls = 0.f;
#pragma unroll
    for (int i = 0; i < 8; i++) ls += __expf(v[i] - m);
    red[t] = ls;
    __syncthreads();
    for (int s = 128; s > 0; s >>= 1) {
        if (t < s) red[t] += red[t + s];
        __syncthreads();
    }
    float inv = 1.f / red[0];
#pragma unroll
    for (int i = 0; i < 8; i++) {
        int s = i * 256 + t;
        float w = __expf(v[i] - m) * inv;
        wl[s] = w;
        if (kcg == 0) out[B * H + b * S + s] = w;
    }
    __syncthreads();

    const int wv = t >> 6, lane = t & 63, qd = lane >> 4, colr = lane & 15;
    const int kc = kcg * 4 + wv;
    float a8[8] = {0.f, 0.f, 0.f, 0.f, 0.f, 0.f, 0.f, 0.f};
    const uint4* base = Abf + ((size_t)(b * 128) * 32 + kc) * 64 + lane;
#pragma unroll 4
    for (int st = 0; st < 128; st++) {
        uint4 f = base[(size_t)st * 2048];
        float w = wl[st * 16 + colr];
        a8[0] += w * __uint_as_float(f.x << 16);
        a8[1] += w * __uint_as_float(f.x & 0xffff0000u);
        a8[2] += w * __uint_as_float(f.y << 16);
        a8[3] += w * __uint_as_float(f.y & 0xffff0000u);
        a8[4] += w * __uint_as_float(f.z << 16);
        a8[5] += w * __uint_as_float(f.z & 0xffff0000u);
        a8[6] += w * __uint_as_float(f.w << 16);
        a8[7] += w * __uint_as_float(f.w & 0xffff0000u);
    }
#pragma unroll
    for (int j = 0; j < 8; j++) {
        float vj = a8[j];
        vj += __shfl_xor(vj, 1, 64);
        vj += __shfl_xor(vj, 2, 64);
        vj += __shfl_xor(vj, 4, 64);
        vj += __shfl_xor(vj, 8, 64);
        a8[j] = vj;
    }
    if (colr == 0) {
        int colbase = kc * 32 + qd * 8;
#pragma unroll
        for (int j = 0; j < 8; j++) out[b * H + colbase + j] = a8[j];
    }
}

// ===========================================================================
// Fallback path (ws too small)
// ===========================================================================
__global__ __launch_bounds__(256, 3) void k2_scores_fb(
    const float* __restrict__ keys, const uint4* __restrict__ UaSw,
    const float* __restrict__ qp, const float* __restrict__ Vaw,
    float* __restrict__ sp) {
    __shared__ uint4 As[2][512];
    __shared__ uint4 Bs[2][512];
    __shared__ float part[2][128];
    const int tid = threadIdx.x;
    const int lane = tid & 63;
    const int wave = tid >> 6;
    const int wm = wave >> 1, wn = wave & 1;
    const int lid = blockIdx.x;
    const int c = lid & 7;
    const int qq = lid >> 3;
    const int nb = qq & 7;
    const int mb = (qq >> 3) * 8 + c;
    const int b = mb >> 4;
    const int s0 = (mb & 15) << 7;
    const int el = tid & 63;
    const int srow0 = s0 + (tid >> 6) * 16 + (el & 15);
    const int srow1 = srow0 + 64;
    const int kofs = ((el >> 4) & 3) * 8;
    const float4* ka0 = (const float4*)(keys + ((size_t)b * S + srow0) * H + kofs);
    const float4* ka1 = (const float4*)(keys + ((size_t)b * S + srow1) * H + kofs);
    const uint4* srcB = UaSw + (size_t)nb * 32 * 512;
    f32x4 acc[4][4];
#pragma unroll
    for (int mt = 0; mt < 4; mt++)
#pragma unroll
        for (int nt = 0; nt < 4; nt++) acc[mt][nt] = (f32x4){0.f, 0.f, 0.f, 0.f};
    float4 x0 = ka0[0], y0 = ka0[1], x1 = ka1[0], y1 = ka1[1];
    async_copy16(srcB + tid,       &Bs[0][tid]);
    async_copy16(srcB + tid + 256, &Bs[0][tid + 256]);
    As[0][tid]       = pack8(x0, y0);
    As[0][tid + 256] = pack8(x1, y1);
    x0 = ka0[8]; y0 = ka0[9]; x1 = ka1[8]; y1 = ka1[9];
    __syncthreads();
    for (int kc = 0; kc < 32; kc++) {
        const int cur = kc & 1, nxt = cur ^ 1;
        if (kc < 31) {
            async_copy16(srcB + (size_t)(kc + 1) * 512 + tid,       &Bs[nxt][tid]);
            async_copy16(srcB + (size_t)(kc + 1) * 512 + tid + 256, &Bs[nxt][tid + 256]);
            As[nxt][tid]       = pack8(x0, y0);
            As[nxt][tid + 256] = pack8(x1, y1);
            if (kc < 30) {
                x0 = ka0[(kc + 2) * 8]; y0 = ka0[(kc + 2) * 8 + 1];
                x1 = ka1[(kc + 2) * 8]; y1 = ka1[(kc + 2) * 8 + 1];
            }
        }
        U4 af[4], bf[4];
#pragma unroll
        for (int mt = 0; mt < 4; mt++) af[mt].u = As[cur][(wm * 4 + mt) * 64 + lane];
#pragma unroll
        for (int nt = 0; nt < 4; nt++) bf[nt].u = Bs[cur][(wn * 4 + nt) * 64 + lane];
#pragma unroll
        for (int mt = 0; mt < 4; mt++)
#pragma unroll
            for (int nt = 0; nt < 4; nt++)
                acc[mt][nt] = __builtin_amdgcn_mfma_f32_16x16x32_bf16(
                    af[mt].b, bf[nt].b, acc[mt][nt], 0, 0, 0);
        __syncthreads();
    }
    const int col = lane & 15, qd = lane >> 4;
    float qv[4], vv[4];
#pragma unroll
    for (int nt = 0; nt < 4; nt++) {
        int n = nb * 128 + (wn * 4 + nt) * 16 + col;
        qv[nt] = qp[b * H + n];
        vv[nt] = Vaw[n];
    }
#pragma unroll
    for (int mt = 0; mt < 4; mt++) {
        float rs[4] = {0.f, 0.f, 0.f, 0.f};
#pragma unroll
        for (int nt = 0; nt < 4; nt++)
#pragma unroll
            for (int r = 0; r < 4; r++)
                rs[r] += ftanh(acc[mt][nt][r] + qv[nt]) * vv[nt];
#pragma unroll
        for (int r = 0; r < 4; r++) {
            float v = rs[r];
            v += __shfl_xor(v, 1, 64);
            v += __shfl_xor(v, 2, 64);
            v += __shfl_xor(v, 4, 64);
            v += __shfl_xor(v, 8, 64);
            if (col == 0) part[wn][wm * 64 + mt * 16 + qd * 4 + r] = v;
        }
    }
    __syncthreads();
    if (tid < 128)
        sp[(size_t)nb * B * S + b * S + s0 + tid] = part[0][tid] + part[1][tid];
}

__global__ __launch_bounds__(256) void k4_ctx_fb(const float* __restrict__ keys,
                                                 const float* __restrict__ sp,
                                                 float* __restrict__ out) {
    int sc = blockIdx.x, b = blockIdx.y;
    int t = threadIdx.x;
    __shared__ float red[256];
    __shared__ float wl[64];
    float v[8];
#pragma unroll
    for (int i = 0; i < 8; i++) {
        int s = i * 256 + t;
        float sum = 0.f;
#pragma unroll
        for (int nb = 0; nb < 8; nb++) sum += sp[(size_t)nb * B * S + b * S + s];
        v[i] = sum;
    }
    float lm = -1e30f;
#pragma unroll
    for (int i = 0; i < 8; i++) lm = fmaxf(lm, v[i]);
    red[t] = lm;
    __syncthreads();
    for (int s = 128; s > 0; s >>= 1) {
        if (t < s) red[t] = fmaxf(red[t], red[t + s]);
        __syncthreads();
    }
    float m = red[0];
    __syncthreads();
    float ls = 0.f;
#pragma unroll
    for (int i = 0; i < 8; i++) ls += __expf(v[i] - m);
    red[t] = ls;
    __syncthreads();
    for (int s = 128; s > 0; s >>= 1) {
        if (t < s) red[t] += red[t + s];
        __syncthreads();
    }
    float inv = 1.f / red[0];
    if (t < 64) {
        int s = sc * 64 + t;
        float sum = 0.f;
#pragma unroll
        for (int nb = 0; nb < 8; nb++) sum += sp[(size_t)nb * B * S + b * S + s];
        float w = __expf(sum - m) * inv;
        wl[t] = w;
        out[B * H + b * S + s] = w;
    }
    __syncthreads();
    const float4* kp = (const float4*)(keys + ((size_t)b * S + sc * 64) * H) + t;
    float4 acc = {0.f, 0.f, 0.f, 0.f};
#pragma unroll 8
    for (int s = 0; s < 64; s++) {
        float4 kv = kp[(size_t)s * 256];
        float w = wl[s];
        acc.x += w * kv.x; acc.y += w * kv.y;
        acc.z += w * kv.z; acc.w += w * kv.w;
    }
    float* dst = out + b * H + t * 4;
    atomicAdd(dst + 0, acc.x);
    atomicAdd(dst + 1, acc.y);
    atomicAdd(dst + 2, acc.z);
    atomicAdd(dst + 3, acc.w);
}

// ---------------------------------------------------------------------------
extern "C" void kernel_launch(void* const* d_in, const int* in_sizes, int n_in,
                              void* d_out, int out_size, void* d_ws, size_t ws_size,
                              hipStream_t stream) {
    const float* query = (const float*)d_in[0];
    const float* keys  = (const float*)d_in[1];
    const float* Wa_w  = (const float*)d_in[2];
    const float* Wa_b  = (const float*)d_in[3];
    const float* Ua_w  = (const float*)d_in[4];
    const float* Ua_b  = (const float*)d_in[5];
    const float* Va_w  = (const float*)d_in[6];
    float* out = (float*)d_out;

    // ws: [0,2MB) UaSw; [2MB,+128KB) qp; [2MB+128KB,+2MB) sp; [8MB,+128MB) Abf
    uint4* UaSw = (uint4*)d_ws;
    float* qp = (float*)((char*)d_ws + (2u << 20));
    float* sp = (float*)((char*)d_ws + (2u << 20) + (128u << 10));
    uint4* Abf = (uint4*)((char*)d_ws + (8u << 20));
    const size_t NEED = (size_t)(8u << 20) + ((size_t)128u << 20);

    if (ws_size >= NEED) {
        ka_swz2<<<4096, 256, 0, stream>>>(keys, Abf);
        k0_swizzle<<<512, 256, 0, stream>>>(Ua_w, UaSw);
        k1_qproj<<<dim3(16, B), 256, 0, stream>>>(query, Wa_w, Wa_b, Ua_b, qp);
        k2_scores9<<<4096, 256, 0, stream>>>(Abf, UaSw, qp, Va_w, sp);
        k4_ctx2<<<dim3(8, B), 256, 0, stream>>>(Abf, sp, out);
    } else {
        hipMemsetAsync(d_out, 0, B * H * sizeof(float), stream);
        k0_swizzle<<<512, 256, 0, stream>>>(Ua_w, UaSw);
        k1_qproj<<<dim3(16, B), 256, 0, stream>>>(query, Wa_w, Wa_b, Ua_b, qp);
        k2_scores_fb<<<4096, 256, 0, stream>>>(keys, UaSw, qp, Va_w, sp);
        k4_ctx_fb<<<dim3(32, B), 256, 0, stream>>>(keys, sp, out);
    }
}